// Round 17
// baseline (922.470 us; speedup 1.0000x reference)
//
#include <hip/hip_runtime.h>
#include <hip/hip_bf16.h>
#include <cstdint>
#include <cstddef>

#define T_TOK 4096
#define HID   2048
#define INTER 768
#define NEXP  64

typedef float  f32x4  __attribute__((ext_vector_type(4)));
typedef __bf16 bf16x8 __attribute__((ext_vector_type(8)));
typedef __bf16 bf16x4 __attribute__((ext_vector_type(4)));

__device__ __forceinline__ void gl16(const void* g, void* l) {
  __builtin_amdgcn_global_load_lds((const __attribute__((address_space(1))) void*)g,
                                   (__attribute__((address_space(3))) void*)l, 16, 0, 0);
}

#define BAR() do { asm volatile("" ::: "memory"); __builtin_amdgcn_s_barrier(); asm volatile("" ::: "memory"); } while (0)

// ---------------- small helper kernels ----------------

__global__ void zero_meta_kernel(int* counts, int* fill) {
  int t = threadIdx.x;
  if (t < NEXP) { counts[t] = 0; fill[t] = 0; }
}

__global__ void scan_kernel(const int* __restrict__ counts, int* __restrict__ offsets,
                            int* __restrict__ tb) {
  if (threadIdx.x == 0) {
    int s = 0, ts = 0;
    for (int e = 0; e < NEXP; e++) {
      offsets[e] = s; tb[e] = ts;
      s += counts[e]; ts += (counts[e] + 255) >> 8;
    }
    offsets[NEXP] = s; tb[NEXP] = ts;
  }
}

__global__ void scatter_kernel(const int* __restrict__ topk_id, const float* __restrict__ topk_w,
                               const int* __restrict__ offsets, int* __restrict__ fill,
                               int* __restrict__ pair_tok, float* __restrict__ pair_w,
                               int* __restrict__ pair_pos) {
  int i = blockIdx.x * 256 + threadIdx.x;  // 0..32767
  int e = topk_id[i];
  int pos = offsets[e] + atomicAdd(&fill[e], 1);
  pair_tok[pos] = i >> 3;
  pair_w[pos]  = topk_w[i];
  pair_pos[i]  = pos;
}

// ---------------- per-wave weight transpose tile (validated transpose_cvt body) ----------------
// mode 0 (w_down): granules [e][nb=n/128][kt][q][col128]
// mode 1 (w_gate_up): granules [e][nb6][kt][q][rp256], rp = isup*128 + (hcol&127)

__device__ __forceinline__ void transpose_tile(
    const float* __restrict__ src, __bf16* __restrict__ dst,
    int Kd, int Nd, int mode, int wid, char* Sw, int lane) {
  const int g = lane >> 4, nq = lane & 15;
  const int NT = Nd >> 6, KT = Kd >> 6, NB = Nd >> 7;
  int tpe = KT * NT;
  int e = wid / tpe;
  int rem = wid - e * tpe;
  int kt = rem / NT;
  int nt = rem - kt * NT;
  const float* sp = src + ((size_t)e * Kd + (size_t)kt * 64) * Nd + nt * 64;

  float4 vv[16];
  #pragma unroll
  for (int kq = 0; kq < 16; kq++)
    vv[kq] = *(const float4*)(sp + (size_t)(kq * 4 + g) * Nd + nq * 4);

  const int n_l = nq * 4 + g;
  #pragma unroll
  for (int kq = 0; kq < 16; kq++) {
    float4 v = vv[kq];
    float t0 = __shfl_xor(v.x, 32), t1 = __shfl_xor(v.y, 32);
    float t2 = __shfl_xor(v.z, 32), t3 = __shfl_xor(v.w, 32);
    bool hi2 = (g & 2) != 0;
    float a0 = hi2 ? t2 : v.x, a1 = hi2 ? t3 : v.y;
    float a2 = hi2 ? v.z : t0, a3 = hi2 ? v.w : t1;
    float s0 = __shfl_xor(a0, 16), s1 = __shfl_xor(a1, 16);
    float s2 = __shfl_xor(a2, 16), s3 = __shfl_xor(a3, 16);
    bool odd = (g & 1) != 0;
    float u0 = odd ? s1 : a0, u1 = odd ? a1 : s0;
    float u2 = odd ? s3 : a2, u3 = odd ? a3 : s2;
    bf16x4 b; b[0] = (__bf16)u0; b[1] = (__bf16)u1; b[2] = (__bf16)u2; b[3] = (__bf16)u3;
    *(bf16x4*)(Sw + n_l * 128 + ((kq ^ (n_l & 15)) << 3)) = b;
  }
  asm volatile("s_waitcnt lgkmcnt(0)" ::: "memory");
  __builtin_amdgcn_sched_barrier(0);

  if (mode == 0) {
    uint4* gdst = (uint4*)dst + ((((size_t)e * NB + (nt >> 1)) * KT + kt) << 10) + ((nt & 1) << 6) + lane;
    #pragma unroll
    for (int q = 0; q < 8; q++) {
      int p0 = (2 * q) ^ (lane & 15), p1 = (2 * q + 1) ^ (lane & 15);
      uint2 lo = *(const uint2*)(Sw + lane * 128 + (p0 << 3));
      uint2 hi = *(const uint2*)(Sw + lane * 128 + (p1 << 3));
      gdst[q * 128] = make_uint4(lo.x, lo.y, hi.x, hi.y);
    }
  } else {
    int n = nt * 64 + lane;
    int isup = (n >= INTER) ? 1 : 0;
    int hcol = isup ? n - INTER : n;
    int nb = hcol >> 7, ho = hcol & 127;
    int rp = isup * 128 + ho;
    uint4* gdst = (uint4*)dst + ((((size_t)e * 6 + nb) * KT + kt) << 11) + rp;
    #pragma unroll
    for (int q = 0; q < 8; q++) {
      int p0 = (2 * q) ^ (lane & 15), p1 = (2 * q + 1) ^ (lane & 15);
      uint2 lo = *(const uint2*)(Sw + lane * 128 + (p0 << 3));
      uint2 hi = *(const uint2*)(Sw + lane * 128 + (p1 << 3));
      gdst[q * 256] = make_uint4(lo.x, lo.y, hi.x, hi.y);
    }
  }
}

// ---------------- FAT1: router (blocks 0..255) || T1 wgu transpose (blocks 256..) ----------------

__global__ __launch_bounds__(256) void fat1_kernel(
    const float* __restrict__ x, const float* __restrict__ gw, __bf16* __restrict__ xbf,
    int* __restrict__ topk_id, float* __restrict__ topk_w, int* __restrict__ counts,
    const float* __restrict__ wgu, __bf16* __restrict__ w2gu) {
  __shared__ __align__(16) char fsm[32768];
  const int tid = threadIdx.x, lane = tid & 63, wv = tid >> 6;

  if (blockIdx.x >= 256) {
    transpose_tile(wgu, w2gu, HID, 2 * INTER, 1,
                   ((int)blockIdx.x - 256) * 4 + wv, fsm + wv * 8192, lane);
    return;
  }

  // ---- router: fp32 logits + wave-wide top-8; also emits xbf (fused cvt) ----
  float (*gs)[65] = (float (*)[65])fsm;            // 64x65 f32 = 16640 B
  float (*xs)[65] = (float (*)[65])(fsm + 16640);  // 16x65 f32 = 4160 B
  const int tblk = blockIdx.x * 16;

  float acc[4] = {0.f, 0.f, 0.f, 0.f};
  for (int kc = 0; kc < HID; kc += 64) {
    #pragma unroll
    for (int i = 0; i < 4; i++) {
      int r = tid >> 2;
      int c = (tid & 3) * 16 + i * 4;
      float4 v = *(const float4*)(gw + (size_t)r * HID + kc + c);
      gs[r][c + 0] = v.x; gs[r][c + 1] = v.y; gs[r][c + 2] = v.z; gs[r][c + 3] = v.w;
    }
    {
      int r = tid >> 4;
      int c = (tid & 15) * 4;
      float4 v = *(const float4*)(x + (size_t)(tblk + r) * HID + kc + c);
      xs[r][c + 0] = v.x; xs[r][c + 1] = v.y; xs[r][c + 2] = v.z; xs[r][c + 3] = v.w;
      bf16x4 b;
      b[0] = (__bf16)v.x; b[1] = (__bf16)v.y; b[2] = (__bf16)v.z; b[3] = (__bf16)v.w;
      *(bf16x4*)(xbf + (size_t)(tblk + r) * HID + kc + c) = b;    // fused x -> bf16
    }
    __syncthreads();
    #pragma unroll 8
    for (int k = 0; k < 64; k++) {
      float g = gs[lane][k];
      #pragma unroll
      for (int j = 0; j < 4; j++) acc[j] = fmaf(xs[wv * 4 + j][k], g, acc[j]);
    }
    __syncthreads();
  }

  for (int j = 0; j < 4; j++) {
    int t = tblk + wv * 4 + j;
    float vsel = acc[j];
    float m1 = 0.f, denom = 0.f;
    int myid = 0; float myw = 0.f;
    for (int s = 0; s < 8; s++) {
      float bv = vsel; int bi = lane;
      #pragma unroll
      for (int off = 32; off > 0; off >>= 1) {
        float ov = __shfl_xor(bv, off);
        int   oi = __shfl_xor(bi, off);
        if (ov > bv || (ov == bv && oi < bi)) { bv = ov; bi = oi; }
      }
      if (s == 0) m1 = bv;
      float ev = __expf(bv - m1);
      denom += ev;
      if (lane == s)  { myid = bi; myw = ev; }
      if (lane == bi) vsel = -3.402823466e38f;
    }
    if (lane < 8) {
      topk_id[t * 8 + lane] = myid;
      topk_w[t * 8 + lane]  = myw / denom;
      atomicAdd(&counts[myid], 1);
    }
  }
}

// ---------------- FAT2: 2-phase BK=32 GEMM1 (blocks 0..nwgG1-1) || T2 wd transpose ----------------
// G1: gather(xbf) @ Wgu -> SwiGLU -> H2. 512 thr (8 waves 2m x 4n), BM=256, BK=32,
// per-wave 128m x (32 gate + 32 up). LDS 80KB + VGPR 128 -> 2 blocks/CU.
// 2 phases/K-step (halved barriers vs r16): P1 issues B(ks+1) both units, reads
// af(m0)+bg+bu, 16 MFMA; P2 issues A(ks+2) both units, reads af(m1), 16 MFMA.
// FIFO queue entering P1(ks) = [A(ks)2 < B(ks)2 < A(ks+1)2] -> vmcnt(2) proves
// A(ks)+B(ks). P2: no wait. Tail P1(63): vmcnt(0). Post-loop BAR protects the
// epilogue's smem writes from P2(63)'s slot-0 reads.

__global__ __launch_bounds__(512, 2) void fat2_kernel(
    const uint4* __restrict__ xbf4, const uint4* __restrict__ w2gu,
    const int* __restrict__ offsets, const int* __restrict__ tb,
    const int* __restrict__ pair_tok, const float* __restrict__ pair_w,
    uint4* __restrict__ H2,
    const float* __restrict__ wd, __bf16* __restrict__ w2d, int nwgG1) {
  __shared__ __align__(16) char smem[81920];
  const int tid = threadIdx.x, lane = tid & 63, w = tid >> 6;
  const int bid = blockIdx.x;

  if (bid >= nwgG1) {
    transpose_tile(wd, w2d, INTER, HID, 0,
                   (bid - nwgG1) * 8 + w, smem + w * 8192, lane);
    return;
  }

  const int q8 = nwgG1 >> 3, r8 = nwgG1 & 7;
  const int xcd = bid & 7, idx = bid >> 3;
  const int wg = (xcd < r8 ? xcd * (q8 + 1) : r8 * (q8 + 1) + (xcd - r8) * q8) + idx;
  const int mt0 = wg % 3, t1 = wg / 3, nb = t1 % 6, e = t1 / 6;
  const int off = offsets[e], cnt = offsets[e + 1] - off;
  const uint4* Bb = w2gu + (size_t)(e * 6 + nb) * 65536;
  const int wm = w >> 2, wn = w & 3;
  const int g = lane >> 4, nq = lane & 15;
  const int sq = w >> 1, sr = w & 1;            // staging roles
  const int aoff  = (sq << 12) + (sr << 11);    // (sq*256 + sr*128)*16
  const int boffg = (sq << 8) + (sr << 6);      // B granule base

#define STA1(s, ks) gl16(rA1 + (size_t)(ks) * 4, smem + (s) * 16384 + aoff + (lane << 4))
#define STA2(s, ks) gl16(rA2 + (size_t)(ks) * 4, smem + (s) * 16384 + aoff + 1024 + (lane << 4))
#define STBG(pb, ks) gl16(Bb + (size_t)(ks) * 1024 + boffg + lane, \
                          smem + 49152 + (pb) * 16384 + (boffg << 4) + (lane << 4))
#define STBU(pb, ks) gl16(Bb + (size_t)(ks) * 1024 + boffg + 128 + lane, \
                          smem + 49152 + (pb) * 16384 + ((boffg + 128) << 4) + (lane << 4))

  for (int mt = mt0; mt * 256 < cnt; mt += 3) {
    const int rows = min(256, cnt - mt * 256);
    const int m0 = mt * 256;
    const int rm = rows - 1;
    // per-lane gather bases: row r1 = sr*128+lane (A1), r2 = r1+64 (A2); granule col = sq
    const int tok1 = pair_tok[off + m0 + min(sr * 128 + lane, rm)];
    const int tok2 = pair_tok[off + m0 + min(sr * 128 + 64 + lane, rm)];
    const uint4* rA1 = xbf4 + (size_t)tok1 * 256 + sq;
    const uint4* rA2 = xbf4 + (size_t)tok2 * 256 + sq;

    f32x4 ag[8][2], au[8][2];
    #pragma unroll
    for (int i = 0; i < 8; i++)
      #pragma unroll
      for (int j = 0; j < 2; j++)
        #pragma unroll
        for (int q = 0; q < 4; q++) { ag[i][j][q] = 0.f; au[i][j][q] = 0.f; }

    // prologue: queue = [A1_0,A2_0,BG0,BU0,A1_1,A2_1]
    STA1(0, 0); STA2(0, 0); STBG(0, 0); STBU(0, 0); STA1(1, 1); STA2(1, 1);
    for (int ks = 0; ks < 64; ks++) {
      char* bA = smem + (ks % 3) * 16384;
      char* bB = smem + 49152 + (ks & 1) * 16384;
      bf16x8 af[4], bg[2], bu[2];
      // ---- P1: prove A(ks)+B(ks); issue B(ks+1); m0 gate+up ----
      if (ks < 63) asm volatile("s_waitcnt vmcnt(2)" ::: "memory");
      else         asm volatile("s_waitcnt vmcnt(0)" ::: "memory");
      BAR();
      if (ks + 1 < 64) { STBG((ks + 1) & 1, ks + 1); STBU((ks + 1) & 1, ks + 1); }
      #pragma unroll
      for (int mi = 0; mi < 4; mi++)
        af[mi] = *(const bf16x8*)(bA + (g << 12) + ((wm * 128 + mi * 16 + nq) << 4));
      #pragma unroll
      for (int ni = 0; ni < 2; ni++) {
        bg[ni] = *(const bf16x8*)(bB + (g << 12) + ((wn * 32 + ni * 16 + nq) << 4));
        bu[ni] = *(const bf16x8*)(bB + (g << 12) + ((128 + wn * 32 + ni * 16 + nq) << 4));
      }
      __builtin_amdgcn_s_setprio(1);
      #pragma unroll
      for (int mi = 0; mi < 4; mi++)
        #pragma unroll
        for (int ni = 0; ni < 2; ni++) {
          ag[mi][ni] = __builtin_amdgcn_mfma_f32_16x16x32_bf16(af[mi], bg[ni], ag[mi][ni], 0, 0, 0);
          au[mi][ni] = __builtin_amdgcn_mfma_f32_16x16x32_bf16(af[mi], bu[ni], au[mi][ni], 0, 0, 0);
        }
      __builtin_amdgcn_s_setprio(0);
      // ---- P2: no wait; issue A(ks+2); m1 gate+up ----
      BAR();
      if (ks + 2 < 64) { STA1((ks + 2) % 3, ks + 2); STA2((ks + 2) % 3, ks + 2); }
      #pragma unroll
      for (int mi = 0; mi < 4; mi++)
        af[mi] = *(const bf16x8*)(bA + (g << 12) + ((wm * 128 + 64 + mi * 16 + nq) << 4));
      __builtin_amdgcn_s_setprio(1);
      #pragma unroll
      for (int mi = 0; mi < 4; mi++)
        #pragma unroll
        for (int ni = 0; ni < 2; ni++) {
          ag[4 + mi][ni] = __builtin_amdgcn_mfma_f32_16x16x32_bf16(af[mi], bg[ni], ag[4 + mi][ni], 0, 0, 0);
          au[4 + mi][ni] = __builtin_amdgcn_mfma_f32_16x16x32_bf16(af[mi], bu[ni], au[4 + mi][ni], 0, 0, 0);
        }
      __builtin_amdgcn_s_setprio(0);
    }
    BAR();   // P2(63)'s slot-0 reads complete before epilogue smem writes

    // epilogue: h = silu(g)*u*pw -> swizzled LDS (64KB @ offset 0) -> H2 coalesced granule writes
    #pragma unroll
    for (int mi = 0; mi < 8; mi++) {
      const int mrow = (mi < 4) ? (wm * 128 + mi * 16) : (wm * 128 + 64 + (mi - 4) * 16);
      #pragma unroll
      for (int reg = 0; reg < 4; reg++) {
        int rrow = mrow + g * 4 + reg;
        float pw = (rrow < rows) ? pair_w[off + m0 + rrow] : 0.f;
        #pragma unroll
        for (int ni = 0; ni < 2; ni++) {
          float gv = ag[mi][ni][reg];
          float uv = au[mi][ni][reg];
          float sv = gv / (1.f + __expf(-gv));
          int col = wn * 32 + ni * 16 + nq;
          *(__bf16*)(smem + rrow * 256 + ((col * 2) ^ ((rrow & 7) << 4))) = (__bf16)(sv * uv * pw);
        }
      }
    }
    BAR();
    {
      uint4* Hb = H2 + (size_t)(tb[e] + mt) * 24576 + nb * 16 * 256;
      #pragma unroll
      for (int i = 0; i < 8; i++) {
        int idx2 = tid + i * 512;
        int gx = idx2 >> 8, row = idx2 & 255;
        uint4 v = *(const uint4*)(smem + row * 256 + ((gx * 16) ^ ((row & 7) << 4)));
        Hb[gx * 256 + row] = v;
      }
    }
    BAR();   // protect smem before next mt's staging
  }
#undef STA1
#undef STA2
#undef STBG
#undef STBU
}

// ---------------- 2-phase BK=32 grouped GEMM2: H2 @ Wd -> ybuf (per-pair bf16 rows) ----------------
// Mirror of fat2-G1 2-phase schedule: 24 K-steps, A 3-ring @ 0/16K/32K, B double @ 48K/64K.
// P1 issues BG+BH(ks+1), reads af(m0)+bl+bh, vmcnt(2) (tail 0); P2 issues A(ks+2), reads af(m1).

__global__ __launch_bounds__(512, 2) void gemm2_kernel(
    const uint4* __restrict__ H2, const uint4* __restrict__ w2d,
    const int* __restrict__ offsets, const int* __restrict__ tb,
    __bf16* __restrict__ ybuf, int e0, int nwg) {
  __shared__ __align__(16) char smem[81920];
  const int bid = blockIdx.x;
  const int q8 = nwg >> 3, r8 = nwg & 7;
  const int xcd = bid & 7, idx = bid >> 3;
  const int wg = (xcd < r8 ? xcd * (q8 + 1) : r8 * (q8 + 1) + (xcd - r8) * q8) + idx;
  const int mt0 = wg % 3, t1 = wg / 3, nb2 = t1 % 8, ez = t1 / 8;
  const int e = e0 + ez;
  const int off = offsets[e], cnt = offsets[e + 1] - off;
  const int pnl0 = ez * 16 + nb2 * 2;
  const uint4* B0 = w2d + (size_t)pnl0 * 12288;
  const uint4* B1 = B0 + 12288;
  const int tid = threadIdx.x, lane = tid & 63, w = tid >> 6;
  const int wm = w >> 2, wn = w & 3;
  const int g = lane >> 4, nq = lane & 15;
  const int sq = w >> 1, sr = w & 1;
  const int aoff = (sq << 12) + (sr << 11);

#define S2A1(s, ks) gl16(Ab + (size_t)(ks) * 1024 + (sq << 8) + (sr << 7) + lane, \
                         smem + (s) * 16384 + aoff + (lane << 4))
#define S2A2(s, ks) gl16(Ab + (size_t)(ks) * 1024 + (sq << 8) + (sr << 7) + 64 + lane, \
                         smem + (s) * 16384 + aoff + 1024 + (lane << 4))
#define S2BG(pb, ks) gl16(B0 + (size_t)(ks) * 512 + (sq << 7) + (sr << 6) + lane, \
                          smem + 49152 + (pb) * 16384 + (sq << 12) + (sr << 10) + (lane << 4))
#define S2BH(pb, ks) gl16(B1 + (size_t)(ks) * 512 + (sq << 7) + (sr << 6) + lane, \
                          smem + 49152 + (pb) * 16384 + (sq << 12) + 2048 + (sr << 10) + (lane << 4))

  for (int mt = mt0; mt * 256 < cnt; mt += 3) {
    const int rows = min(256, cnt - mt * 256);
    const uint4* Ab = H2 + (size_t)(tb[e] + mt) * 24576;

    f32x4 a0[8][2], a1[8][2];
    #pragma unroll
    for (int i = 0; i < 8; i++)
      #pragma unroll
      for (int j = 0; j < 2; j++)
        #pragma unroll
        for (int q = 0; q < 4; q++) { a0[i][j][q] = 0.f; a1[i][j][q] = 0.f; }

    // prologue: queue = [A1_0,A2_0,BG0,BH0,A1_1,A2_1]
    S2A1(0, 0); S2A2(0, 0); S2BG(0, 0); S2BH(0, 0); S2A1(1, 1); S2A2(1, 1);
    for (int ks = 0; ks < 24; ks++) {
      char* bA = smem + (ks % 3) * 16384;
      char* bB = smem + 49152 + (ks & 1) * 16384;
      bf16x8 af[4], bl[2], bh[2];
      // ---- P1: prove A(ks)+B(ks); issue B(ks+1); m0 both panels ----
      if (ks < 23) asm volatile("s_waitcnt vmcnt(2)" ::: "memory");
      else         asm volatile("s_waitcnt vmcnt(0)" ::: "memory");
      BAR();
      if (ks + 1 < 24) { S2BG((ks + 1) & 1, ks + 1); S2BH((ks + 1) & 1, ks + 1); }
      #pragma unroll
      for (int mi = 0; mi < 4; mi++)
        af[mi] = *(const bf16x8*)(bA + (g << 12) + ((wm * 128 + mi * 16 + nq) << 4));
      #pragma unroll
      for (int ni = 0; ni < 2; ni++) {
        bl[ni] = *(const bf16x8*)(bB + (g << 12) + ((wn * 32 + ni * 16 + nq) << 4));
        bh[ni] = *(const bf16x8*)(bB + (g << 12) + ((128 + wn * 32 + ni * 16 + nq) << 4));
      }
      __builtin_amdgcn_s_setprio(1);
      #pragma unroll
      for (int mi = 0; mi < 4; mi++)
        #pragma unroll
        for (int ni = 0; ni < 2; ni++) {
          a0[mi][ni] = __builtin_amdgcn_mfma_f32_16x16x32_bf16(af[mi], bl[ni], a0[mi][ni], 0, 0, 0);
          a1[mi][ni] = __builtin_amdgcn_mfma_f32_16x16x32_bf16(af[mi], bh[ni], a1[mi][ni], 0, 0, 0);
        }
      __builtin_amdgcn_s_setprio(0);
      // ---- P2: no wait; issue A(ks+2); m1 both panels ----
      BAR();
      if (ks + 2 < 24) { S2A1((ks + 2) % 3, ks + 2); S2A2((ks + 2) % 3, ks + 2); }
      #pragma unroll
      for (int mi = 0; mi < 4; mi++)
        af[mi] = *(const bf16x8*)(bA + (g << 12) + ((wm * 128 + 64 + mi * 16 + nq) << 4));
      __builtin_amdgcn_s_setprio(1);
      #pragma unroll
      for (int mi = 0; mi < 4; mi++)
        #pragma unroll
        for (int ni = 0; ni < 2; ni++) {
          a0[4 + mi][ni] = __builtin_amdgcn_mfma_f32_16x16x32_bf16(af[mi], bl[ni], a0[4 + mi][ni], 0, 0, 0);
          a1[4 + mi][ni] = __builtin_amdgcn_mfma_f32_16x16x32_bf16(af[mi], bh[ni], a1[4 + mi][ni], 0, 0, 0);
        }
      __builtin_amdgcn_s_setprio(0);
    }

    const int m0 = mt * 256;
    #pragma unroll
    for (int mi = 0; mi < 8; mi++) {
      const int mrow = (mi < 4) ? (wm * 128 + mi * 16) : (wm * 128 + 64 + (mi - 4) * 16);
      #pragma unroll
      for (int reg = 0; reg < 4; reg++) {
        int rrow = mrow + g * 4 + reg;
        if (rrow < rows) {
          __bf16* yrow = ybuf + (size_t)(off + m0 + rrow) * HID + nb2 * 256 + wn * 32;
          #pragma unroll
          for (int ni = 0; ni < 2; ni++) {
            yrow[ni * 16 + nq]       = (__bf16)a0[mi][ni][reg];
            yrow[128 + ni * 16 + nq] = (__bf16)a1[mi][ni][reg];
          }
        }
      }
    }
  }
#undef S2A1
#undef S2A2
#undef S2BG
#undef S2BH
}

// ---------------- final reduce: out[t] = sum over the token's 8 pair rows (bf16 y) ----------------

__global__ __launch_bounds__(256) void reduce_kernel(
    const __bf16* __restrict__ ybuf, const int* __restrict__ pair_pos,
    float* __restrict__ out) {
  const int t = blockIdx.x, j = threadIdx.x;   // 8 cols per thread
  const int* pp = pair_pos + t * 8;
  float s[8] = {0.f, 0.f, 0.f, 0.f, 0.f, 0.f, 0.f, 0.f};
  #pragma unroll
  for (int k = 0; k < 8; k++) {
    bf16x8 v = *(const bf16x8*)(ybuf + (size_t)pp[k] * HID + j * 8);
    #pragma unroll
    for (int c = 0; c < 8; c++) s[c] += (float)v[c];
  }
  float4 o0 = make_float4(s[0], s[1], s[2], s[3]);
  float4 o1 = make_float4(s[4], s[5], s[6], s[7]);
  *(float4*)(out + (size_t)t * HID + j * 8) = o0;
  *(float4*)(out + (size_t)t * HID + j * 8 + 4) = o1;
}

// ---------------- launch ----------------
// FAT1 = router (256 blocks, first) || T1 wgu transpose (12288 blocks).
// FAT2 = G1 2-phase BK=32 2-blocks/CU (1152 blocks, first) || T2 wd transpose (3072 blocks).
// GEMM2 = 2-phase BK=32 2-blocks/CU (1536 blocks).

extern "C" void kernel_launch(void* const* d_in, const int* in_sizes, int n_in,
                              void* d_out, int out_size, void* d_ws, size_t ws_size,
                              hipStream_t stream) {
  const float* x   = (const float*)d_in[0];
  const float* gw  = (const float*)d_in[1];
  const float* wgu = (const float*)d_in[2];
  const float* wd  = (const float*)d_in[3];
  float* out = (float*)d_out;

  char* ws = (char*)d_ws;
  int*   counts   = (int*)(ws + 0);
  int*   fill     = (int*)(ws + 256);
  int*   offsets  = (int*)(ws + 512);
  int*   tb       = (int*)(ws + 1024);
  int*   topk_id  = (int*)(ws + 4096);
  float* topk_w   = (float*)(ws + 135168);
  int*   pair_tok = (int*)(ws + 266240);
  float* pair_w   = (float*)(ws + 397312);
  int*   pair_pos = (int*)(ws + 528384);
  __bf16* xbf  = (__bf16*)(ws + 1048576);
  __bf16* ybuf = (__bf16*)(ws + 68157440);
  uint4*  H2   = (uint4*)(ws + 537919488);
  const size_t w2_base = 613416960ull;
  __bf16* w2gu = (__bf16*)(ws + w2_base);
  __bf16* w2d  = (__bf16*)(ws + w2_base + 64ull * 6291456ull);

  zero_meta_kernel<<<1, 128, 0, stream>>>(counts, fill);
  fat1_kernel<<<256 + 12288, 256, 0, stream>>>(x, gw, xbf, topk_id, topk_w, counts, wgu, w2gu);
  scan_kernel<<<1, 64, 0, stream>>>(counts, offsets, tb);
  scatter_kernel<<<128, 256, 0, stream>>>(topk_id, topk_w, offsets, fill, pair_tok, pair_w, pair_pos);

  fat2_kernel<<<1152 + 3072, 512, 0, stream>>>((const uint4*)xbf, (const uint4*)w2gu,
                                               offsets, tb, pair_tok, pair_w, H2,
                                               wd, w2d, 1152);
  gemm2_kernel<<<1536, 512, 0, stream>>>(H2, (const uint4*)w2d, offsets, tb, ybuf, 0, 1536);
  reduce_kernel<<<T_TOK, 256, 0, stream>>>(ybuf, pair_pos, out);
}

// Round 18
// 895.522 us; speedup vs baseline: 1.0301x; 1.0301x over previous
//
#include <hip/hip_runtime.h>
#include <hip/hip_bf16.h>
#include <cstdint>
#include <cstddef>

#define T_TOK 4096
#define HID   2048
#define INTER 768
#define NEXP  64

typedef float  f32x4  __attribute__((ext_vector_type(4)));
typedef __bf16 bf16x8 __attribute__((ext_vector_type(8)));
typedef __bf16 bf16x4 __attribute__((ext_vector_type(4)));

__device__ __forceinline__ void gl16(const void* g, void* l) {
  __builtin_amdgcn_global_load_lds((const __attribute__((address_space(1))) void*)g,
                                   (__attribute__((address_space(3))) void*)l, 16, 0, 0);
}

#define BAR() do { asm volatile("" ::: "memory"); __builtin_amdgcn_s_barrier(); asm volatile("" ::: "memory"); } while (0)

// ---------------- small helper kernels ----------------

__global__ void zero_meta_kernel(int* counts, int* fill) {
  int t = threadIdx.x;
  if (t < NEXP) { counts[t] = 0; fill[t] = 0; }
}

__global__ void scan_kernel(const int* __restrict__ counts, int* __restrict__ offsets,
                            int* __restrict__ tb) {
  if (threadIdx.x == 0) {
    int s = 0, ts = 0;
    for (int e = 0; e < NEXP; e++) {
      offsets[e] = s; tb[e] = ts;
      s += counts[e]; ts += (counts[e] + 255) >> 8;
    }
    offsets[NEXP] = s; tb[NEXP] = ts;
  }
}

__global__ void scatter_kernel(const int* __restrict__ topk_id, const float* __restrict__ topk_w,
                               const int* __restrict__ offsets, int* __restrict__ fill,
                               int* __restrict__ pair_tok, float* __restrict__ pair_w,
                               int* __restrict__ pair_pos) {
  int i = blockIdx.x * 256 + threadIdx.x;  // 0..32767
  int e = topk_id[i];
  int pos = offsets[e] + atomicAdd(&fill[e], 1);
  pair_tok[pos] = i >> 3;
  pair_w[pos]  = topk_w[i];
  pair_pos[i]  = pos;
}

// ---------------- per-wave weight transpose tile (validated transpose_cvt body) ----------------
// mode 0 (w_down): granules [e][nb=n/128][kt][q][col128]
// mode 1 (w_gate_up): granules [e][nb6][kt][q][rp256], rp = isup*128 + (hcol&127)

__device__ __forceinline__ void transpose_tile(
    const float* __restrict__ src, __bf16* __restrict__ dst,
    int Kd, int Nd, int mode, int wid, char* Sw, int lane) {
  const int g = lane >> 4, nq = lane & 15;
  const int NT = Nd >> 6, KT = Kd >> 6, NB = Nd >> 7;
  int tpe = KT * NT;
  int e = wid / tpe;
  int rem = wid - e * tpe;
  int kt = rem / NT;
  int nt = rem - kt * NT;
  const float* sp = src + ((size_t)e * Kd + (size_t)kt * 64) * Nd + nt * 64;

  float4 vv[16];
  #pragma unroll
  for (int kq = 0; kq < 16; kq++)
    vv[kq] = *(const float4*)(sp + (size_t)(kq * 4 + g) * Nd + nq * 4);

  const int n_l = nq * 4 + g;
  #pragma unroll
  for (int kq = 0; kq < 16; kq++) {
    float4 v = vv[kq];
    float t0 = __shfl_xor(v.x, 32), t1 = __shfl_xor(v.y, 32);
    float t2 = __shfl_xor(v.z, 32), t3 = __shfl_xor(v.w, 32);
    bool hi2 = (g & 2) != 0;
    float a0 = hi2 ? t2 : v.x, a1 = hi2 ? t3 : v.y;
    float a2 = hi2 ? v.z : t0, a3 = hi2 ? v.w : t1;
    float s0 = __shfl_xor(a0, 16), s1 = __shfl_xor(a1, 16);
    float s2 = __shfl_xor(a2, 16), s3 = __shfl_xor(a3, 16);
    bool odd = (g & 1) != 0;
    float u0 = odd ? s1 : a0, u1 = odd ? a1 : s0;
    float u2 = odd ? s3 : a2, u3 = odd ? a3 : s2;
    bf16x4 b; b[0] = (__bf16)u0; b[1] = (__bf16)u1; b[2] = (__bf16)u2; b[3] = (__bf16)u3;
    *(bf16x4*)(Sw + n_l * 128 + ((kq ^ (n_l & 15)) << 3)) = b;
  }
  asm volatile("s_waitcnt lgkmcnt(0)" ::: "memory");
  __builtin_amdgcn_sched_barrier(0);

  if (mode == 0) {
    uint4* gdst = (uint4*)dst + ((((size_t)e * NB + (nt >> 1)) * KT + kt) << 10) + ((nt & 1) << 6) + lane;
    #pragma unroll
    for (int q = 0; q < 8; q++) {
      int p0 = (2 * q) ^ (lane & 15), p1 = (2 * q + 1) ^ (lane & 15);
      uint2 lo = *(const uint2*)(Sw + lane * 128 + (p0 << 3));
      uint2 hi = *(const uint2*)(Sw + lane * 128 + (p1 << 3));
      gdst[q * 128] = make_uint4(lo.x, lo.y, hi.x, hi.y);
    }
  } else {
    int n = nt * 64 + lane;
    int isup = (n >= INTER) ? 1 : 0;
    int hcol = isup ? n - INTER : n;
    int nb = hcol >> 7, ho = hcol & 127;
    int rp = isup * 128 + ho;
    uint4* gdst = (uint4*)dst + ((((size_t)e * 6 + nb) * KT + kt) << 11) + rp;
    #pragma unroll
    for (int q = 0; q < 8; q++) {
      int p0 = (2 * q) ^ (lane & 15), p1 = (2 * q + 1) ^ (lane & 15);
      uint2 lo = *(const uint2*)(Sw + lane * 128 + (p0 << 3));
      uint2 hi = *(const uint2*)(Sw + lane * 128 + (p1 << 3));
      gdst[q * 256] = make_uint4(lo.x, lo.y, hi.x, hi.y);
    }
  }
}

// ---------------- FAT1: router (blocks 0..255) || T1 wgu transpose (blocks 256..) ----------------

__global__ __launch_bounds__(256) void fat1_kernel(
    const float* __restrict__ x, const float* __restrict__ gw, __bf16* __restrict__ xbf,
    int* __restrict__ topk_id, float* __restrict__ topk_w, int* __restrict__ counts,
    const float* __restrict__ wgu, __bf16* __restrict__ w2gu) {
  __shared__ __align__(16) char fsm[32768];
  const int tid = threadIdx.x, lane = tid & 63, wv = tid >> 6;

  if (blockIdx.x >= 256) {
    transpose_tile(wgu, w2gu, HID, 2 * INTER, 1,
                   ((int)blockIdx.x - 256) * 4 + wv, fsm + wv * 8192, lane);
    return;
  }

  // ---- router: fp32 logits + wave-wide top-8; also emits xbf (fused cvt) ----
  float (*gs)[65] = (float (*)[65])fsm;            // 64x65 f32 = 16640 B
  float (*xs)[65] = (float (*)[65])(fsm + 16640);  // 16x65 f32 = 4160 B
  const int tblk = blockIdx.x * 16;

  float acc[4] = {0.f, 0.f, 0.f, 0.f};
  for (int kc = 0; kc < HID; kc += 64) {
    #pragma unroll
    for (int i = 0; i < 4; i++) {
      int r = tid >> 2;
      int c = (tid & 3) * 16 + i * 4;
      float4 v = *(const float4*)(gw + (size_t)r * HID + kc + c);
      gs[r][c + 0] = v.x; gs[r][c + 1] = v.y; gs[r][c + 2] = v.z; gs[r][c + 3] = v.w;
    }
    {
      int r = tid >> 4;
      int c = (tid & 15) * 4;
      float4 v = *(const float4*)(x + (size_t)(tblk + r) * HID + kc + c);
      xs[r][c + 0] = v.x; xs[r][c + 1] = v.y; xs[r][c + 2] = v.z; xs[r][c + 3] = v.w;
      bf16x4 b;
      b[0] = (__bf16)v.x; b[1] = (__bf16)v.y; b[2] = (__bf16)v.z; b[3] = (__bf16)v.w;
      *(bf16x4*)(xbf + (size_t)(tblk + r) * HID + kc + c) = b;    // fused x -> bf16
    }
    __syncthreads();
    #pragma unroll 8
    for (int k = 0; k < 64; k++) {
      float g = gs[lane][k];
      #pragma unroll
      for (int j = 0; j < 4; j++) acc[j] = fmaf(xs[wv * 4 + j][k], g, acc[j]);
    }
    __syncthreads();
  }

  for (int j = 0; j < 4; j++) {
    int t = tblk + wv * 4 + j;
    float vsel = acc[j];
    float m1 = 0.f, denom = 0.f;
    int myid = 0; float myw = 0.f;
    for (int s = 0; s < 8; s++) {
      float bv = vsel; int bi = lane;
      #pragma unroll
      for (int off = 32; off > 0; off >>= 1) {
        float ov = __shfl_xor(bv, off);
        int   oi = __shfl_xor(bi, off);
        if (ov > bv || (ov == bv && oi < bi)) { bv = ov; bi = oi; }
      }
      if (s == 0) m1 = bv;
      float ev = __expf(bv - m1);
      denom += ev;
      if (lane == s)  { myid = bi; myw = ev; }
      if (lane == bi) vsel = -3.402823466e38f;
    }
    if (lane < 8) {
      topk_id[t * 8 + lane] = myid;
      topk_w[t * 8 + lane]  = myw / denom;
      atomicAdd(&counts[myid], 1);
    }
  }
}

// ---------------- FAT2: 4-phase BK=32 GEMM1 (blocks 0..nwgG1-1) || T2 wd transpose ----------------
// G1: gather(xbf) @ Wgu -> SwiGLU -> H2. 512 thr (8 waves 2m x 4n), BM=256, BK=32,
// per-wave 128m x (32 gate + 32 up). LDS 80KB -> 2 blocks/CU (cross-block overlap).
// launch_bounds(512,2): VGPR budget 128 (min-waves=4 capped at 64 and spilled acc -> r14 lesson).
// Buffers: A 3-ring @ 0/16K/32K, B double @ 48K/64K. Stage roles: sq=w>>1, sr=w&1.
// Issue per tile ks: A->BG(ks+1), B->BU(ks+1), C->A1(ks+2), D->A2(ks+2).
// Waits: phase A vmcnt(3) proves BG(ks)+all A(ks); phase B vmcnt(3) proves BU(ks);
// C/D none. Tail ks=63: vmcnt(1)/vmcnt(0).

__global__ __launch_bounds__(512, 2) void fat2_kernel(
    const uint4* __restrict__ xbf4, const uint4* __restrict__ w2gu,
    const int* __restrict__ offsets, const int* __restrict__ tb,
    const int* __restrict__ pair_tok, const float* __restrict__ pair_w,
    uint4* __restrict__ H2,
    const float* __restrict__ wd, __bf16* __restrict__ w2d, int nwgG1) {
  __shared__ __align__(16) char smem[81920];
  const int tid = threadIdx.x, lane = tid & 63, w = tid >> 6;
  const int bid = blockIdx.x;

  if (bid >= nwgG1) {
    transpose_tile(wd, w2d, INTER, HID, 0,
                   (bid - nwgG1) * 8 + w, smem + w * 8192, lane);
    return;
  }

  const int q8 = nwgG1 >> 3, r8 = nwgG1 & 7;
  const int xcd = bid & 7, idx = bid >> 3;
  const int wg = (xcd < r8 ? xcd * (q8 + 1) : r8 * (q8 + 1) + (xcd - r8) * q8) + idx;
  const int mt0 = wg % 3, t1 = wg / 3, nb = t1 % 6, e = t1 / 6;
  const int off = offsets[e], cnt = offsets[e + 1] - off;
  const uint4* Bb = w2gu + (size_t)(e * 6 + nb) * 65536;
  const int wm = w >> 2, wn = w & 3;
  const int g = lane >> 4, nq = lane & 15;
  const int sq = w >> 1, sr = w & 1;            // staging roles
  const int aoff  = (sq << 12) + (sr << 11);    // (sq*256 + sr*128)*16
  const int boffg = (sq << 8) + (sr << 6);      // B granule base

#define STA1(s, ks) gl16(rA1 + (size_t)(ks) * 4, smem + (s) * 16384 + aoff + (lane << 4))
#define STA2(s, ks) gl16(rA2 + (size_t)(ks) * 4, smem + (s) * 16384 + aoff + 1024 + (lane << 4))
#define STBG(pb, ks) gl16(Bb + (size_t)(ks) * 1024 + boffg + lane, \
                          smem + 49152 + (pb) * 16384 + (boffg << 4) + (lane << 4))
#define STBU(pb, ks) gl16(Bb + (size_t)(ks) * 1024 + boffg + 128 + lane, \
                          smem + 49152 + (pb) * 16384 + ((boffg + 128) << 4) + (lane << 4))

  for (int mt = mt0; mt * 256 < cnt; mt += 3) {
    const int rows = min(256, cnt - mt * 256);
    const int m0 = mt * 256;
    const int rm = rows - 1;
    // per-lane gather bases: row r1 = sr*128+lane (A1), r2 = r1+64 (A2); granule col = sq
    const int tok1 = pair_tok[off + m0 + min(sr * 128 + lane, rm)];
    const int tok2 = pair_tok[off + m0 + min(sr * 128 + 64 + lane, rm)];
    const uint4* rA1 = xbf4 + (size_t)tok1 * 256 + sq;
    const uint4* rA2 = xbf4 + (size_t)tok2 * 256 + sq;

    f32x4 ag[8][2], au[8][2];
    #pragma unroll
    for (int i = 0; i < 8; i++)
      #pragma unroll
      for (int j = 0; j < 2; j++)
        #pragma unroll
        for (int q = 0; q < 4; q++) { ag[i][j][q] = 0.f; au[i][j][q] = 0.f; }

    // prologue: queue = [A1_0,A2_0,BG0,BU0,A1_1,A2_1]
    STA1(0, 0); STA2(0, 0); STBG(0, 0); STBU(0, 0); STA1(1, 1); STA2(1, 1);
    for (int ks = 0; ks < 64; ks++) {
      char* bA = smem + (ks % 3) * 16384;
      char* bB = smem + 49152 + (ks & 1) * 16384;
      bf16x8 af[4], bg[2], bu[2];
      // ---- phase A: prove BG(ks)+A(ks); issue BG(ks+1); gate m0 ----
      if (ks < 63) asm volatile("s_waitcnt vmcnt(3)" ::: "memory");
      else         asm volatile("s_waitcnt vmcnt(1)" ::: "memory");
      BAR();
      if (ks + 1 < 64) STBG((ks + 1) & 1, ks + 1);
      #pragma unroll
      for (int mi = 0; mi < 4; mi++)
        af[mi] = *(const bf16x8*)(bA + (g << 12) + ((wm * 128 + mi * 16 + nq) << 4));
      #pragma unroll
      for (int ni = 0; ni < 2; ni++)
        bg[ni] = *(const bf16x8*)(bB + (g << 12) + ((wn * 32 + ni * 16 + nq) << 4));
      __builtin_amdgcn_s_setprio(1);
      #pragma unroll
      for (int mi = 0; mi < 4; mi++)
        #pragma unroll
        for (int ni = 0; ni < 2; ni++)
          ag[mi][ni] = __builtin_amdgcn_mfma_f32_16x16x32_bf16(af[mi], bg[ni], ag[mi][ni], 0, 0, 0);
      __builtin_amdgcn_s_setprio(0);
      // ---- phase B: prove BU(ks); issue BU(ks+1); up m0 ----
      if (ks < 63) asm volatile("s_waitcnt vmcnt(3)" ::: "memory");
      else         asm volatile("s_waitcnt vmcnt(0)" ::: "memory");
      BAR();
      if (ks + 1 < 64) STBU((ks + 1) & 1, ks + 1);
      #pragma unroll
      for (int ni = 0; ni < 2; ni++)
        bu[ni] = *(const bf16x8*)(bB + (g << 12) + ((128 + wn * 32 + ni * 16 + nq) << 4));
      __builtin_amdgcn_s_setprio(1);
      #pragma unroll
      for (int mi = 0; mi < 4; mi++)
        #pragma unroll
        for (int ni = 0; ni < 2; ni++)
          au[mi][ni] = __builtin_amdgcn_mfma_f32_16x16x32_bf16(af[mi], bu[ni], au[mi][ni], 0, 0, 0);
      __builtin_amdgcn_s_setprio(0);
      // ---- phase C: no wait; issue A1(ks+2); gate m1 ----
      BAR();
      if (ks + 2 < 64) STA1((ks + 2) % 3, ks + 2);
      #pragma unroll
      for (int mi = 0; mi < 4; mi++)
        af[mi] = *(const bf16x8*)(bA + (g << 12) + ((wm * 128 + 64 + mi * 16 + nq) << 4));
      __builtin_amdgcn_s_setprio(1);
      #pragma unroll
      for (int mi = 0; mi < 4; mi++)
        #pragma unroll
        for (int ni = 0; ni < 2; ni++)
          ag[4 + mi][ni] = __builtin_amdgcn_mfma_f32_16x16x32_bf16(af[mi], bg[ni], ag[4 + mi][ni], 0, 0, 0);
      __builtin_amdgcn_s_setprio(0);
      // ---- phase D: no wait; issue A2(ks+2); up m1 ----
      BAR();
      if (ks + 2 < 64) STA2((ks + 2) % 3, ks + 2);
      __builtin_amdgcn_s_setprio(1);
      #pragma unroll
      for (int mi = 0; mi < 4; mi++)
        #pragma unroll
        for (int ni = 0; ni < 2; ni++)
          au[4 + mi][ni] = __builtin_amdgcn_mfma_f32_16x16x32_bf16(af[mi], bu[ni], au[4 + mi][ni], 0, 0, 0);
      __builtin_amdgcn_s_setprio(0);
    }

    // epilogue: h = silu(g)*u*pw -> swizzled LDS (64KB @ offset 0) -> H2 coalesced granule writes
    #pragma unroll
    for (int mi = 0; mi < 8; mi++) {
      const int mrow = (mi < 4) ? (wm * 128 + mi * 16) : (wm * 128 + 64 + (mi - 4) * 16);
      #pragma unroll
      for (int reg = 0; reg < 4; reg++) {
        int rrow = mrow + g * 4 + reg;
        float pw = (rrow < rows) ? pair_w[off + m0 + rrow] : 0.f;
        #pragma unroll
        for (int ni = 0; ni < 2; ni++) {
          float gv = ag[mi][ni][reg];
          float uv = au[mi][ni][reg];
          float sv = gv / (1.f + __expf(-gv));
          int col = wn * 32 + ni * 16 + nq;
          *(__bf16*)(smem + rrow * 256 + ((col * 2) ^ ((rrow & 7) << 4))) = (__bf16)(sv * uv * pw);
        }
      }
    }
    BAR();
    {
      uint4* Hb = H2 + (size_t)(tb[e] + mt) * 24576 + nb * 16 * 256;
      #pragma unroll
      for (int i = 0; i < 8; i++) {
        int idx2 = tid + i * 512;
        int gx = idx2 >> 8, row = idx2 & 255;
        uint4 v = *(const uint4*)(smem + row * 256 + ((gx * 16) ^ ((row & 7) << 4)));
        Hb[gx * 256 + row] = v;
      }
    }
    BAR();   // protect smem before next mt's staging
  }
#undef STA1
#undef STA2
#undef STBG
#undef STBU
}

// ---------------- 4-phase BK=32 grouped GEMM2: H2 @ Wd -> ybuf (per-pair bf16 rows) ----------------
// Mirror of fat2-G1 schedule: 24 K-steps, A 3-ring 16KB @ 0/16K/32K (contiguous H2 reads),
// B double 16KB @ 48K/64K (panel0 -> LDS rows 0..127, panel1 -> 128..255). LDS 80KB ->
// 2 blocks/CU. Stage roles sq=w>>1, sr=w&1; 1 gl16/thread/stage. Waits identical to G1.

__global__ __launch_bounds__(512, 2) void gemm2_kernel(
    const uint4* __restrict__ H2, const uint4* __restrict__ w2d,
    const int* __restrict__ offsets, const int* __restrict__ tb,
    __bf16* __restrict__ ybuf, int e0, int nwg) {
  __shared__ __align__(16) char smem[81920];
  const int bid = blockIdx.x;
  const int q8 = nwg >> 3, r8 = nwg & 7;
  const int xcd = bid & 7, idx = bid >> 3;
  const int wg = (xcd < r8 ? xcd * (q8 + 1) : r8 * (q8 + 1) + (xcd - r8) * q8) + idx;
  const int mt0 = wg % 3, t1 = wg / 3, nb2 = t1 % 8, ez = t1 / 8;
  const int e = e0 + ez;
  const int off = offsets[e], cnt = offsets[e + 1] - off;
  const int pnl0 = ez * 16 + nb2 * 2;
  const uint4* B0 = w2d + (size_t)pnl0 * 12288;
  const uint4* B1 = B0 + 12288;
  const int tid = threadIdx.x, lane = tid & 63, w = tid >> 6;
  const int wm = w >> 2, wn = w & 3;
  const int g = lane >> 4, nq = lane & 15;
  const int sq = w >> 1, sr = w & 1;
  const int aoff = (sq << 12) + (sr << 11);

#define S2A1(s, ks) gl16(Ab + (size_t)(ks) * 1024 + (sq << 8) + (sr << 7) + lane, \
                         smem + (s) * 16384 + aoff + (lane << 4))
#define S2A2(s, ks) gl16(Ab + (size_t)(ks) * 1024 + (sq << 8) + (sr << 7) + 64 + lane, \
                         smem + (s) * 16384 + aoff + 1024 + (lane << 4))
#define S2BG(pb, ks) gl16(B0 + (size_t)(ks) * 512 + (sq << 7) + (sr << 6) + lane, \
                          smem + 49152 + (pb) * 16384 + (sq << 12) + (sr << 10) + (lane << 4))
#define S2BH(pb, ks) gl16(B1 + (size_t)(ks) * 512 + (sq << 7) + (sr << 6) + lane, \
                          smem + 49152 + (pb) * 16384 + (sq << 12) + 2048 + (sr << 10) + (lane << 4))

  for (int mt = mt0; mt * 256 < cnt; mt += 3) {
    const int rows = min(256, cnt - mt * 256);
    const uint4* Ab = H2 + (size_t)(tb[e] + mt) * 24576;

    f32x4 a0[8][2], a1[8][2];
    #pragma unroll
    for (int i = 0; i < 8; i++)
      #pragma unroll
      for (int j = 0; j < 2; j++)
        #pragma unroll
        for (int q = 0; q < 4; q++) { a0[i][j][q] = 0.f; a1[i][j][q] = 0.f; }

    // prologue: queue = [A1_0,A2_0,BG0,BH0,A1_1,A2_1]
    S2A1(0, 0); S2A2(0, 0); S2BG(0, 0); S2BH(0, 0); S2A1(1, 1); S2A2(1, 1);
    for (int ks = 0; ks < 24; ks++) {
      char* bA = smem + (ks % 3) * 16384;
      char* bB = smem + 49152 + (ks & 1) * 16384;
      bf16x8 af[4], bl[2], bh[2];
      // ---- phase A: prove BG(ks)+A(ks); issue BG(ks+1); panel0 m0 ----
      if (ks < 23) asm volatile("s_waitcnt vmcnt(3)" ::: "memory");
      else         asm volatile("s_waitcnt vmcnt(1)" ::: "memory");
      BAR();
      if (ks + 1 < 24) S2BG((ks + 1) & 1, ks + 1);
      #pragma unroll
      for (int mi = 0; mi < 4; mi++)
        af[mi] = *(const bf16x8*)(bA + (g << 12) + ((wm * 128 + mi * 16 + nq) << 4));
      #pragma unroll
      for (int ni = 0; ni < 2; ni++)
        bl[ni] = *(const bf16x8*)(bB + (g << 12) + ((wn * 32 + ni * 16 + nq) << 4));
      __builtin_amdgcn_s_setprio(1);
      #pragma unroll
      for (int mi = 0; mi < 4; mi++)
        #pragma unroll
        for (int ni = 0; ni < 2; ni++)
          a0[mi][ni] = __builtin_amdgcn_mfma_f32_16x16x32_bf16(af[mi], bl[ni], a0[mi][ni], 0, 0, 0);
      __builtin_amdgcn_s_setprio(0);
      // ---- phase B: prove BH(ks); issue BH(ks+1); panel1 m0 ----
      if (ks < 23) asm volatile("s_waitcnt vmcnt(3)" ::: "memory");
      else         asm volatile("s_waitcnt vmcnt(0)" ::: "memory");
      BAR();
      if (ks + 1 < 24) S2BH((ks + 1) & 1, ks + 1);
      #pragma unroll
      for (int ni = 0; ni < 2; ni++)
        bh[ni] = *(const bf16x8*)(bB + (g << 12) + ((128 + wn * 32 + ni * 16 + nq) << 4));
      __builtin_amdgcn_s_setprio(1);
      #pragma unroll
      for (int mi = 0; mi < 4; mi++)
        #pragma unroll
        for (int ni = 0; ni < 2; ni++)
          a1[mi][ni] = __builtin_amdgcn_mfma_f32_16x16x32_bf16(af[mi], bh[ni], a1[mi][ni], 0, 0, 0);
      __builtin_amdgcn_s_setprio(0);
      // ---- phase C: no wait; issue A1(ks+2); panel0 m1 ----
      BAR();
      if (ks + 2 < 24) S2A1((ks + 2) % 3, ks + 2);
      #pragma unroll
      for (int mi = 0; mi < 4; mi++)
        af[mi] = *(const bf16x8*)(bA + (g << 12) + ((wm * 128 + 64 + mi * 16 + nq) << 4));
      __builtin_amdgcn_s_setprio(1);
      #pragma unroll
      for (int mi = 0; mi < 4; mi++)
        #pragma unroll
        for (int ni = 0; ni < 2; ni++)
          a0[4 + mi][ni] = __builtin_amdgcn_mfma_f32_16x16x32_bf16(af[mi], bl[ni], a0[4 + mi][ni], 0, 0, 0);
      __builtin_amdgcn_s_setprio(0);
      // ---- phase D: no wait; issue A2(ks+2); panel1 m1 ----
      BAR();
      if (ks + 2 < 24) S2A2((ks + 2) % 3, ks + 2);
      __builtin_amdgcn_s_setprio(1);
      #pragma unroll
      for (int mi = 0; mi < 4; mi++)
        #pragma unroll
        for (int ni = 0; ni < 2; ni++)
          a1[4 + mi][ni] = __builtin_amdgcn_mfma_f32_16x16x32_bf16(af[mi], bh[ni], a1[4 + mi][ni], 0, 0, 0);
      __builtin_amdgcn_s_setprio(0);
    }

    const int m0 = mt * 256;
    #pragma unroll
    for (int mi = 0; mi < 8; mi++) {
      const int mrow = (mi < 4) ? (wm * 128 + mi * 16) : (wm * 128 + 64 + (mi - 4) * 16);
      #pragma unroll
      for (int reg = 0; reg < 4; reg++) {
        int rrow = mrow + g * 4 + reg;
        if (rrow < rows) {
          __bf16* yrow = ybuf + (size_t)(off + m0 + rrow) * HID + nb2 * 256 + wn * 32;
          #pragma unroll
          for (int ni = 0; ni < 2; ni++) {
            yrow[ni * 16 + nq]       = (__bf16)a0[mi][ni][reg];
            yrow[128 + ni * 16 + nq] = (__bf16)a1[mi][ni][reg];
          }
        }
      }
    }
  }
#undef S2A1
#undef S2A2
#undef S2BG
#undef S2BH
}

// ---------------- final reduce: out[t] = sum over the token's 8 pair rows (bf16 y) ----------------

__global__ __launch_bounds__(256) void reduce_kernel(
    const __bf16* __restrict__ ybuf, const int* __restrict__ pair_pos,
    float* __restrict__ out) {
  const int t = blockIdx.x, j = threadIdx.x;   // 8 cols per thread
  const int* pp = pair_pos + t * 8;
  float s[8] = {0.f, 0.f, 0.f, 0.f, 0.f, 0.f, 0.f, 0.f};
  #pragma unroll
  for (int k = 0; k < 8; k++) {
    bf16x8 v = *(const bf16x8*)(ybuf + (size_t)pp[k] * HID + j * 8);
    #pragma unroll
    for (int c = 0; c < 8; c++) s[c] += (float)v[c];
  }
  float4 o0 = make_float4(s[0], s[1], s[2], s[3]);
  float4 o1 = make_float4(s[4], s[5], s[6], s[7]);
  *(float4*)(out + (size_t)t * HID + j * 8) = o0;
  *(float4*)(out + (size_t)t * HID + j * 8 + 4) = o1;
}

// ---------------- launch ----------------
// FAT1 = router (256 blocks, first) || T1 wgu transpose (12288 blocks).
// FAT2 = G1 BK=32 2-blocks/CU (1152 blocks, first) || T2 wd transpose (3072 blocks).
// GEMM2 = BK=32 2-blocks/CU (1536 blocks).

extern "C" void kernel_launch(void* const* d_in, const int* in_sizes, int n_in,
                              void* d_out, int out_size, void* d_ws, size_t ws_size,
                              hipStream_t stream) {
  const float* x   = (const float*)d_in[0];
  const float* gw  = (const float*)d_in[1];
  const float* wgu = (const float*)d_in[2];
  const float* wd  = (const float*)d_in[3];
  float* out = (float*)d_out;

  char* ws = (char*)d_ws;
  int*   counts   = (int*)(ws + 0);
  int*   fill     = (int*)(ws + 256);
  int*   offsets  = (int*)(ws + 512);
  int*   tb       = (int*)(ws + 1024);
  int*   topk_id  = (int*)(ws + 4096);
  float* topk_w   = (float*)(ws + 135168);
  int*   pair_tok = (int*)(ws + 266240);
  float* pair_w   = (float*)(ws + 397312);
  int*   pair_pos = (int*)(ws + 528384);
  __bf16* xbf  = (__bf16*)(ws + 1048576);
  __bf16* ybuf = (__bf16*)(ws + 68157440);
  uint4*  H2   = (uint4*)(ws + 537919488);
  const size_t w2_base = 613416960ull;
  __bf16* w2gu = (__bf16*)(ws + w2_base);
  __bf16* w2d  = (__bf16*)(ws + w2_base + 64ull * 6291456ull);

  zero_meta_kernel<<<1, 128, 0, stream>>>(counts, fill);
  fat1_kernel<<<256 + 12288, 256, 0, stream>>>(x, gw, xbf, topk_id, topk_w, counts, wgu, w2gu);
  scan_kernel<<<1, 64, 0, stream>>>(counts, offsets, tb);
  scatter_kernel<<<128, 256, 0, stream>>>(topk_id, topk_w, offsets, fill, pair_tok, pair_w, pair_pos);

  fat2_kernel<<<1152 + 3072, 512, 0, stream>>>((const uint4*)xbf, (const uint4*)w2gu,
                                               offsets, tb, pair_tok, pair_w, H2,
                                               wd, w2d, 1152);
  gemm2_kernel<<<1536, 512, 0, stream>>>(H2, (const uint4*)w2d, offsets, tb, ybuf, 0, 1536);
  reduce_kernel<<<T_TOK, 256, 0, stream>>>(ybuf, pair_pos, out);
}